// Round 11
// baseline (59.601 us; speedup 1.0000x reference)
//
#include <hip/hip_runtime.h>

#define OUT_F 11008
#define IN_F  4096
#define RB    16               // rows per block (4 per wave)
#define KSTEP 256              // k per tile: 1 KB per row
#define NSTEP (IN_F / KSTEP)   // 16 tiles

// R10: weights stream through LDS via async global_load_lds (16B variant) —
// zero VGPR cost for the weight pipeline (R4/R8 showed register prefetch
// buffers either cross the 128-VGPR cliff or stay too shallow).
// Block = 256 threads = 4 waves; wave w owns rows [blk*16 + w*4, +4) x
// 8 batches x FULL K (rows split across waves -> no K-combine epilogue).
// LDS: double-buffered [2][16][256] int tile = 32 KB -> 4 blocks/CU cap.
// Per iter t: issue x(t) (8x float4, L2-hot) FIRST, then stage(t+1) (4x
// global_load_lds, wave-uniform LDS base + lane*16, linear layout), then
// ds_read w(t) + FMA. The FMA's x-wait is vmcnt(4) -> staging stays in
// flight; sole drain is the compiler's vmcnt(0) at __syncthreads (m97
// pattern: no other waits get inserted before ds_read).
// zero-point folded: out = s*(dot - zp*rowsum(x_b)) + bias, rowsum in-loop.
// NOTE: plain __launch_bounds__ — ",N" variants forced spills (R3).
__device__ __forceinline__ void gl_lds16(const int* gsrc, void* ldst) {
    __builtin_amdgcn_global_load_lds(
        (const __attribute__((address_space(1))) void*)gsrc,
        (__attribute__((address_space(3))) void*)ldst,
        16, 0, 0);
}

__global__ __launch_bounds__(256) void qlinear_kernel(
        const float* __restrict__ in, const int* __restrict__ qw,
        const int* __restrict__ zp, const float* __restrict__ scale,
        const float* __restrict__ bias, float* __restrict__ out) {
    const int lane = threadIdx.x & 63;
    const int wave = threadIdx.x >> 6;       // 0..3
    const int row0 = blockIdx.x * RB;        // block's first output row
    const int wr   = wave * 4;               // wave's first row within block
    const int l4   = lane * 4;

    __shared__ int wlds[2][RB][KSTEP];       // 32 KB double-buffered tile

    const int*   qb = qw + (size_t)(row0 + wr) * IN_F + l4;  // wave's rows
    const float* xp = in + l4;

    // stage tile 0 into buffer 0 (each wave stages its own 4 rows)
    #pragma unroll
    for (int r = 0; r < 4; ++r)
        gl_lds16(qb + (size_t)r * IN_F, &wlds[0][wr + r][0]);

    float acc[4][8];
    float asum[8];
    #pragma unroll
    for (int r = 0; r < 4; ++r)
        #pragma unroll
        for (int b = 0; b < 8; ++b) acc[r][b] = 0.f;
    #pragma unroll
    for (int b = 0; b < 8; ++b) asum[b] = 0.f;

    __syncthreads();   // tile 0 staged (vmcnt drain at barrier)

    #pragma unroll
    for (int t = 0; t < NSTEP; ++t) {
        const int c = t & 1, n = c ^ 1;

        // x(t): issued FIRST -> the FMA's x-wait is vmcnt(4), which leaves
        // the newer staging loads in flight.
        float4 x[8];
        #pragma unroll
        for (int b = 0; b < 8; ++b)
            x[b] = *reinterpret_cast<const float4*>(xp + b * IN_F + t * KSTEP);

        // stage(t+1): async, no VGPR round-trip
        if (t + 1 < NSTEP) {
            #pragma unroll
            for (int r = 0; r < 4; ++r)
                gl_lds16(qb + (size_t)r * IN_F + (t + 1) * KSTEP,
                         &wlds[n][wr + r][0]);
        }

        // w(t) from LDS: canonical contiguous ds_read_b128 pattern
        int4 wv[4];
        #pragma unroll
        for (int r = 0; r < 4; ++r)
            wv[r] = *reinterpret_cast<const int4*>(&wlds[c][wr + r][l4]);

        float f[4][4];
        #pragma unroll
        for (int r = 0; r < 4; ++r) {
            f[r][0] = (float)wv[r].x;
            f[r][1] = (float)wv[r].y;
            f[r][2] = (float)wv[r].z;
            f[r][3] = (float)wv[r].w;
        }
        #pragma unroll
        for (int b = 0; b < 8; ++b) {
            const float4 xv = x[b];
            asum[b] += (xv.x + xv.y) + (xv.z + xv.w);
            #pragma unroll
            for (int r = 0; r < 4; ++r)
                acc[r][b] += f[r][0] * xv.x + f[r][1] * xv.y
                           + f[r][2] * xv.z + f[r][3] * xv.w;
        }

        __syncthreads();   // next tile staged; buf[c] free for restage
    }

    // --- cross-lane reduce of 32 accumulators (register-halving tree):
    // 5 levels -> lane l holds index (l&31) over its 32-lane half; +xor32
    // -> full 64-lane sum on lanes 0..31. index = r*8 + b.
    float v[32];
    #pragma unroll
    for (int r = 0; r < 4; ++r)
        #pragma unroll
        for (int b = 0; b < 8; ++b) v[r * 8 + b] = acc[r][b];

    #pragma unroll
    for (int k = 0; k < 5; ++k) {
        const bool hi = (lane >> k) & 1;
        const int  nn = 32 >> k;
        #pragma unroll
        for (int i = 0; i < 32; ++i) {
            if (i < nn / 2) {
                float keep = hi ? v[2 * i + 1] : v[2 * i];
                float send = hi ? v[2 * i]     : v[2 * i + 1];
                v[i] = keep + __shfl_xor(send, 1 << k);
            }
        }
    }
    const float total = v[0] + __shfl_xor(v[0], 32);

    // --- reduce 8 row-sum accumulators -> rowsum of batch (lane&7)
    float s8[8];
    #pragma unroll
    for (int b = 0; b < 8; ++b) s8[b] = asum[b];
    #pragma unroll
    for (int k = 0; k < 3; ++k) {
        const bool hi = (lane >> k) & 1;
        const int  nn = 8 >> k;
        #pragma unroll
        for (int i = 0; i < 8; ++i) {
            if (i < nn / 2) {
                float keep = hi ? s8[2 * i + 1] : s8[2 * i];
                float send = hi ? s8[2 * i]     : s8[2 * i + 1];
                s8[i] = keep + __shfl_xor(send, 1 << k);
            }
        }
    }
    float S = s8[0];
    S += __shfl_xor(S, 8);
    S += __shfl_xor(S, 16);
    S += __shfl_xor(S, 32);   // full rowsum of batch (lane&7)

    if (lane < 32) {
        const int r = lane >> 3;          // 0..3
        const int b = lane & 7;           // 0..7
        const int o = row0 + wr + r;
        out[(size_t)b * OUT_F + o] =
            scale[o] * (total - (float)zp[o] * S) + bias[o];
    }
}

extern "C" void kernel_launch(void* const* d_in, const int* in_sizes, int n_in,
                              void* d_out, int out_size, void* d_ws, size_t ws_size,
                              hipStream_t stream) {
    const float* in    = (const float*)d_in[0];
    const int*   qw    = (const int*)  d_in[1];
    const int*   zp    = (const int*)  d_in[2];
    const float* scale = (const float*)d_in[3];
    const float* bias  = (const float*)d_in[4];
    float*       out   = (float*)d_out;

    const int blocks = OUT_F / RB;   // 688 blocks x 4 waves (row-split)
    qlinear_kernel<<<blocks, 256, 0, stream>>>(in, qw, zp, scale, bias, out);
}